// Round 1
// baseline (543.297 us; speedup 1.0000x reference)
//
#include <hip/hip_runtime.h>

#define COUT 128  // both layers have 128 output channels

// ---------------- graph preprocessing ----------------

__global__ void init_kernel(float* deg, int* cnt, int n) {
  int i = blockIdx.x * blockDim.x + threadIdx.x;
  if (i < n) { deg[i] = 1.0f; cnt[i] = 0; }  // self-loop weight 1
}

__global__ void edge_count_kernel(const int* __restrict__ dst, const float* __restrict__ ew,
                                  float* deg, int* cnt, int E) {
  int e = blockIdx.x * blockDim.x + threadIdx.x;
  if (e < E) {
    int d = dst[e];
    atomicAdd(&deg[d], ew[e]);
    atomicAdd(&cnt[d], 1);
  }
}

__global__ void rsqrt_kernel(float* deg, int n) {
  int i = blockIdx.x * blockDim.x + threadIdx.x;
  if (i < n) { float d = deg[i]; deg[i] = d > 0.f ? rsqrtf(d) : 0.f; }
}

// one-block exclusive scan of cnt -> rowptr (and a second copy into fill)
__global__ void scan_kernel(const int* __restrict__ cnt, int* __restrict__ rowptr,
                            int* __restrict__ fill, int n) {
  __shared__ int buf[1024];
  __shared__ int carry_s;
  int tid = threadIdx.x;
  if (tid == 0) carry_s = 0;
  __syncthreads();
  for (int base = 0; base < n; base += 1024) {
    int i = base + tid;
    int v = (i < n) ? cnt[i] : 0;
    buf[tid] = v;
    __syncthreads();
    for (int off = 1; off < 1024; off <<= 1) {
      int t = (tid >= off) ? buf[tid - off] : 0;
      __syncthreads();
      buf[tid] += t;
      __syncthreads();
    }
    int incl = buf[tid];
    int carry = carry_s;
    if (i < n) {
      int ex = carry + incl - v;
      rowptr[i] = ex;
      fill[i] = ex;
    }
    __syncthreads();
    if (tid == 1023) carry_s = carry + incl;
    __syncthreads();
  }
  if (tid == 0) rowptr[n] = carry_s;
}

__global__ void scatter_kernel(const int* __restrict__ src, const int* __restrict__ dst,
                               const float* __restrict__ ew, const float* __restrict__ dinv,
                               int* fill, int* __restrict__ col, float* __restrict__ wout, int E) {
  int e = blockIdx.x * blockDim.x + threadIdx.x;
  if (e < E) {
    int s = src[e], d = dst[e];
    int pos = atomicAdd(&fill[d], 1);
    col[pos] = s;
    wout[pos] = dinv[s] * ew[e] * dinv[d];
  }
}

// ---------------- dense GEMM: C[n][128] = A[n][CIN] @ W[CIN][128] ----------------

template <int CIN>
__global__ __launch_bounds__(256) void gemm_kernel(const float* __restrict__ A,
                                                   const float* __restrict__ W,
                                                   float* __restrict__ C, int n) {
  const int TN = 64;  // rows per block
  __shared__ float As[TN][16];
  __shared__ float Ws[16][COUT];
  int row0 = blockIdx.x * TN;
  int tid = threadIdx.x;
  int cq = tid & 31;  // col quad: cols cq*4 .. cq*4+3
  int rg = tid >> 5;  // row group: rows rg*8 .. rg*8+7
  float acc[8][4] = {};
  for (int k0 = 0; k0 < CIN; k0 += 16) {
    for (int t = tid; t < TN * 16; t += 256) {
      int r = t >> 4, kk = t & 15;
      int row = row0 + r;
      As[r][kk] = (row < n) ? A[(size_t)row * CIN + k0 + kk] : 0.f;
    }
    for (int t = tid; t < 16 * COUT; t += 256) {
      int kk = t >> 7, c = t & 127;
      Ws[kk][c] = W[(size_t)(k0 + kk) * COUT + c];
    }
    __syncthreads();
#pragma unroll
    for (int kk = 0; kk < 16; ++kk) {
      float wv[4];
#pragma unroll
      for (int j = 0; j < 4; ++j) wv[j] = Ws[kk][cq * 4 + j];
#pragma unroll
      for (int i = 0; i < 8; ++i) {
        float av = As[rg * 8 + i][kk];
#pragma unroll
        for (int j = 0; j < 4; ++j) acc[i][j] += av * wv[j];
      }
    }
    __syncthreads();
  }
#pragma unroll
  for (int i = 0; i < 8; ++i) {
    int row = row0 + rg * 8 + i;
    if (row < n) {
#pragma unroll
      for (int j = 0; j < 4; ++j) C[(size_t)row * COUT + cq * 4 + j] = acc[i][j];
    }
  }
}

// ---------------- aggregation: out[i] = relu(b + dinv[i]^2*h[i] + sum_e w[e]*h[col[e]]) ----------------

__global__ __launch_bounds__(128) void agg_kernel(const float* __restrict__ h,
                                                  const float* __restrict__ dinv,
                                                  const int* __restrict__ rowptr,
                                                  const int* __restrict__ col,
                                                  const float* __restrict__ w,
                                                  const float* __restrict__ bias,
                                                  float* __restrict__ out, int n) {
  int node = blockIdx.x;
  int c = threadIdx.x;
  float di = dinv[node];
  float acc = di * di * h[(size_t)node * COUT + c];
  int beg = rowptr[node], end = rowptr[node + 1];
  for (int e = beg; e < end; ++e) {
    int s = col[e];
    float ww = w[e];
    acc += ww * h[(size_t)s * COUT + c];
  }
  out[(size_t)node * COUT + c] = fmaxf(acc + bias[c], 0.f);
}

// ---------------- launch ----------------

extern "C" void kernel_launch(void* const* d_in, const int* in_sizes, int n_in,
                              void* d_out, int out_size, void* d_ws, size_t ws_size,
                              hipStream_t stream) {
  const float* x  = (const float*)d_in[0];
  const int*   ei = (const int*)d_in[1];
  const float* ew = (const float*)d_in[2];
  const float* W1 = (const float*)d_in[3];
  const float* b1 = (const float*)d_in[4];
  const float* W2 = (const float*)d_in[5];
  const float* b2 = (const float*)d_in[6];
  float* out = (float*)d_out;

  const int cin = 256;
  const int n = in_sizes[0] / cin;
  const int E = in_sizes[2];
  const int* srcp = ei;
  const int* dstp = ei + E;

  char* base = (char*)d_ws;
  size_t off = 0;
  auto alloc = [&](size_t bytes) -> void* {
    off = (off + 255) & ~(size_t)255;
    void* p = base + off;
    off += bytes;
    return p;
  };
  float* dinv   = (float*)alloc((size_t)n * sizeof(float));
  int*   cnt    = (int*)alloc((size_t)n * sizeof(int));
  int*   rowptr = (int*)alloc((size_t)(n + 1) * sizeof(int));
  int*   fill   = (int*)alloc((size_t)n * sizeof(int));
  int*   col    = (int*)alloc((size_t)E * sizeof(int));
  float* wn     = (float*)alloc((size_t)E * sizeof(float));
  float* bufA   = (float*)alloc((size_t)n * COUT * sizeof(float));
  float* bufB   = (float*)alloc((size_t)n * COUT * sizeof(float));

  const int tb = 256;
  init_kernel<<<(n + tb - 1) / tb, tb, 0, stream>>>(dinv, cnt, n);
  edge_count_kernel<<<(E + tb - 1) / tb, tb, 0, stream>>>(dstp, ew, dinv, cnt, E);
  rsqrt_kernel<<<(n + tb - 1) / tb, tb, 0, stream>>>(dinv, n);
  scan_kernel<<<1, 1024, 0, stream>>>(cnt, rowptr, fill, n);
  scatter_kernel<<<(E + tb - 1) / tb, tb, 0, stream>>>(srcp, dstp, ew, dinv, fill, col, wn, E);

  // layer 1: h = x @ W1 ; aggregate ; +b1 ; relu
  gemm_kernel<256><<<(n + 63) / 64, 256, 0, stream>>>(x, W1, bufA, n);
  agg_kernel<<<n, 128, 0, stream>>>(bufA, dinv, rowptr, col, wn, b1, bufB, n);

  // layer 2: h = h1 @ W2 ; aggregate ; +b2 ; relu
  gemm_kernel<128><<<(n + 63) / 64, 256, 0, stream>>>(bufB, W2, bufA, n);
  agg_kernel<<<n, 128, 0, stream>>>(bufA, dinv, rowptr, col, wn, b2, out, n);
}

// Round 2
// 299.097 us; speedup vs baseline: 1.8165x; 1.8165x over previous
//
#include <hip/hip_runtime.h>

#define COUT 128  // both layers have 128 output channels

typedef unsigned short u16;
typedef unsigned int u32;
typedef __attribute__((ext_vector_type(8))) short bf16x8;
typedef __attribute__((ext_vector_type(4))) float f32x4;

__device__ __forceinline__ u16 f2bf(float f) {
  u32 u = __builtin_bit_cast(u32, f);
  u += 0x7fffu + ((u >> 16) & 1u);  // round-to-nearest-even
  return (u16)(u >> 16);
}
__device__ __forceinline__ float bf2f(u16 h) {
  u32 u = ((u32)h) << 16;
  return __builtin_bit_cast(float, u);
}

// ---------------- graph preprocessing ----------------

__global__ void init_kernel(float* deg, int* cnt, int n) {
  int i = blockIdx.x * blockDim.x + threadIdx.x;
  if (i < n) { deg[i] = 1.0f; cnt[i] = 0; }  // self-loop weight 1
}

__global__ void edge_count_kernel(const int* __restrict__ dst, const float* __restrict__ ew,
                                  float* deg, int* cnt, int E) {
  int e = blockIdx.x * blockDim.x + threadIdx.x;
  if (e < E) {
    int d = dst[e];
    atomicAdd(&deg[d], ew[e]);
    atomicAdd(&cnt[d], 1);
  }
}

__global__ void rsqrt_kernel(float* deg, int n) {
  int i = blockIdx.x * blockDim.x + threadIdx.x;
  if (i < n) { float d = deg[i]; deg[i] = d > 0.f ? rsqrtf(d) : 0.f; }
}

// multi-block scan: (1) per-1024-tile exclusive scan + tile totals
__global__ __launch_bounds__(1024) void scan1_kernel(const int* __restrict__ cnt,
                                                     int* __restrict__ exsc,
                                                     int* __restrict__ partials, int n) {
  __shared__ int buf[1024];
  int tid = threadIdx.x;
  int i = blockIdx.x * 1024 + tid;
  int v = (i < n) ? cnt[i] : 0;
  buf[tid] = v;
  __syncthreads();
  for (int off = 1; off < 1024; off <<= 1) {
    int t = (tid >= off) ? buf[tid - off] : 0;
    __syncthreads();
    buf[tid] += t;
    __syncthreads();
  }
  if (i < n) exsc[i] = buf[tid] - v;
  if (tid == 1023) partials[blockIdx.x] = buf[tid];
}

// (2) scan the tile totals (nb <= 1024), write grand total
__global__ __launch_bounds__(1024) void scan2_kernel(int* partials, int* total_out, int nb) {
  __shared__ int buf[1024];
  int tid = threadIdx.x;
  int v = (tid < nb) ? partials[tid] : 0;
  buf[tid] = v;
  __syncthreads();
  for (int off = 1; off < 1024; off <<= 1) {
    int t = (tid >= off) ? buf[tid - off] : 0;
    __syncthreads();
    buf[tid] += t;
    __syncthreads();
  }
  if (tid < nb) partials[tid] = buf[tid] - v;
  if (tid == 1023) total_out[0] = buf[tid];
}

// (3) add tile offsets, duplicate into fill
__global__ void scan3_kernel(int* __restrict__ rowptr, int* __restrict__ fill,
                             const int* __restrict__ partials, int n) {
  int i = blockIdx.x * blockDim.x + threadIdx.x;
  if (i < n) {
    int r = rowptr[i] + partials[i >> 10];
    rowptr[i] = r;
    fill[i] = r;
  }
}

__global__ void scatter_kernel(const int* __restrict__ src, const int* __restrict__ dst,
                               const float* __restrict__ ew, const float* __restrict__ dinv,
                               int* fill, int2* __restrict__ colw, int E) {
  int e = blockIdx.x * blockDim.x + threadIdx.x;
  if (e < E) {
    int s = src[e], d = dst[e];
    int pos = atomicAdd(&fill[d], 1);
    int2 cw;
    cw.x = s;
    cw.y = __float_as_int(dinv[s] * ew[e] * dinv[d]);
    colw[pos] = cw;
  }
}

// ---------------- W prep: transpose + bf16 hi/lo split ----------------
// W: [K][128] fp32  ->  Wt_h/Wt_l: [128][K] bf16
__global__ void prepw_kernel(const float* __restrict__ W, u16* __restrict__ Wth,
                             u16* __restrict__ Wtl, int K) {
  int idx = blockIdx.x * 256 + threadIdx.x;
  if (idx >= K * COUT) return;
  int nn = idx / K, kk = idx - nn * K;
  float v = W[(size_t)kk * COUT + nn];
  u16 h = f2bf(v);
  Wth[idx] = h;
  Wtl[idx] = f2bf(v - bf2f(h));
}

// ---------------- MFMA GEMM: C[n][128] = A[n][CIN] @ W[CIN][128] ----------------
// bf16 hi/lo split (3 MFMA products) for fp32-class accuracy.
// Tile: BM=64, BN=128, BK=32. 4 waves (2x2), each wave 32x64 = 2x4 MFMA tiles.
// LDS 16B chunks XOR-swizzled: chunk c at (row) holds data chunk c ^ ((row>>1)&3)
// -> all ds_read_b128 fragment reads are 2-way bank aliasing (free).
template <int CIN>
__global__ __launch_bounds__(256) void gemm_mfma_kernel(const float* __restrict__ A,
                                                        const u16* __restrict__ Wth,
                                                        const u16* __restrict__ Wtl,
                                                        float* __restrict__ C, int n) {
  __shared__ u16 Ah[64 * 32], Al[64 * 32], Bh[128 * 32], Bl[128 * 32];
  const int tid = threadIdx.x;
  const int row0 = blockIdx.x * 64;
  const int lane = tid & 63;
  const int w = tid >> 6;
  const int wr = w >> 1, wc = w & 1;
  const int r15 = lane & 15, q4 = lane >> 4;
  const int swz = q4 ^ ((r15 >> 1) & 3);  // read-side chunk swizzle

  f32x4 acc[2][4] = {};

  const int arow = tid >> 2, ac = tid & 3;  // A staging: thread -> (row, data-chunk)
  const int sw_a = ac ^ ((arow >> 1) & 3);
  const bool arow_ok = (row0 + arow) < n;
  const float* aptr = A + (size_t)(row0 + arow) * CIN + ac * 8;

  for (int k0 = 0; k0 < CIN; k0 += 32) {
    if (k0) __syncthreads();
    // ---- stage A: fp32 -> bf16 hi/lo, swizzled ds_write_b128 ----
    float v[8];
    if (arow_ok) {
      float4 p0 = *(const float4*)(aptr + k0);
      float4 p1 = *(const float4*)(aptr + k0 + 4);
      v[0] = p0.x; v[1] = p0.y; v[2] = p0.z; v[3] = p0.w;
      v[4] = p1.x; v[5] = p1.y; v[6] = p1.z; v[7] = p1.w;
    } else {
#pragma unroll
      for (int j = 0; j < 8; ++j) v[j] = 0.f;
    }
    bf16x8 hv, lv;
#pragma unroll
    for (int j = 0; j < 8; ++j) {
      u16 h = f2bf(v[j]);
      hv[j] = (short)h;
      lv[j] = (short)f2bf(v[j] - bf2f(h));
    }
    *(bf16x8*)&Ah[arow * 32 + sw_a * 8] = hv;
    *(bf16x8*)&Al[arow * 32 + sw_a * 8] = lv;
    // ---- stage B: precomputed transposed bf16 hi/lo, swizzled ----
#pragma unroll
    for (int rep = 0; rep < 2; ++rep) {
      int q = tid + rep * 256;
      int nrow = q >> 2, cd = q & 3;
      int dst = nrow * 32 + (cd ^ ((nrow >> 1) & 3)) * 8;
      *(bf16x8*)&Bh[dst] = *(const bf16x8*)(Wth + (size_t)nrow * CIN + k0 + cd * 8);
      *(bf16x8*)&Bl[dst] = *(const bf16x8*)(Wtl + (size_t)nrow * CIN + k0 + cd * 8);
    }
    __syncthreads();
    // ---- fragments + MFMA ----
    bf16x8 aH[2], aL[2], bH[4], bL[4];
#pragma unroll
    for (int mt = 0; mt < 2; ++mt) {
      int r = wr * 32 + mt * 16 + r15;
      int off = r * 32 + swz * 8;
      aH[mt] = *(bf16x8*)&Ah[off];
      aL[mt] = *(bf16x8*)&Al[off];
    }
#pragma unroll
    for (int nt = 0; nt < 4; ++nt) {
      int nn = wc * 64 + nt * 16 + r15;
      int off = nn * 32 + swz * 8;
      bH[nt] = *(bf16x8*)&Bh[off];
      bL[nt] = *(bf16x8*)&Bl[off];
    }
#pragma unroll
    for (int mt = 0; mt < 2; ++mt)
#pragma unroll
      for (int nt = 0; nt < 4; ++nt) {
        acc[mt][nt] = __builtin_amdgcn_mfma_f32_16x16x32_bf16(aH[mt], bH[nt], acc[mt][nt], 0, 0, 0);
        acc[mt][nt] = __builtin_amdgcn_mfma_f32_16x16x32_bf16(aH[mt], bL[nt], acc[mt][nt], 0, 0, 0);
        acc[mt][nt] = __builtin_amdgcn_mfma_f32_16x16x32_bf16(aL[mt], bH[nt], acc[mt][nt], 0, 0, 0);
      }
  }
  // ---- epilogue: C/D layout col=lane&15, row=(lane>>4)*4+reg ----
#pragma unroll
  for (int mt = 0; mt < 2; ++mt) {
    int rbase = row0 + wr * 32 + mt * 16 + q4 * 4;
#pragma unroll
    for (int nt = 0; nt < 4; ++nt) {
      int col = wc * 64 + nt * 16 + r15;
#pragma unroll
      for (int j = 0; j < 4; ++j) {
        int r = rbase + j;
        if (r < n) C[(size_t)r * COUT + col] = acc[mt][nt][j];
      }
    }
  }
}

// ---------------- aggregation: out[i] = relu(b + dinv[i]^2*h[i] + sum_e w*h[col]) ----------------
// 1 wave per node, float2 per lane, 2-edge unroll.
__global__ __launch_bounds__(256) void agg_kernel(const float* __restrict__ h,
                                                  const float* __restrict__ dinv,
                                                  const int* __restrict__ rowptr,
                                                  const int2* __restrict__ colw,
                                                  const float* __restrict__ bias,
                                                  float* __restrict__ out, int n) {
  int node = blockIdx.x * 4 + (threadIdx.x >> 6);
  if (node >= n) return;
  int lane = threadIdx.x & 63;
  float di = dinv[node];
  float2 hv = ((const float2*)(h + (size_t)node * COUT))[lane];
  float ax = di * di * hv.x, ay = di * di * hv.y;
  int e = rowptr[node], end = rowptr[node + 1];
  for (; e + 1 < end; e += 2) {
    int2 c0 = colw[e], c1 = colw[e + 1];
    float2 v0 = ((const float2*)(h + (size_t)c0.x * COUT))[lane];
    float2 v1 = ((const float2*)(h + (size_t)c1.x * COUT))[lane];
    float w0 = __int_as_float(c0.y), w1 = __int_as_float(c1.y);
    ax += w0 * v0.x; ay += w0 * v0.y;
    ax += w1 * v1.x; ay += w1 * v1.y;
  }
  if (e < end) {
    int2 c0 = colw[e];
    float2 v0 = ((const float2*)(h + (size_t)c0.x * COUT))[lane];
    float w0 = __int_as_float(c0.y);
    ax += w0 * v0.x; ay += w0 * v0.y;
  }
  float2 bv = ((const float2*)bias)[lane];
  float2 o;
  o.x = fmaxf(ax + bv.x, 0.f);
  o.y = fmaxf(ay + bv.y, 0.f);
  ((float2*)(out + (size_t)node * COUT))[lane] = o;
}

// ---------------- launch ----------------

extern "C" void kernel_launch(void* const* d_in, const int* in_sizes, int n_in,
                              void* d_out, int out_size, void* d_ws, size_t ws_size,
                              hipStream_t stream) {
  const float* x  = (const float*)d_in[0];
  const int*   ei = (const int*)d_in[1];
  const float* ew = (const float*)d_in[2];
  const float* W1 = (const float*)d_in[3];
  const float* b1 = (const float*)d_in[4];
  const float* W2 = (const float*)d_in[5];
  const float* b2 = (const float*)d_in[6];
  float* out = (float*)d_out;

  const int cin = 256;
  const int n = in_sizes[0] / cin;
  const int E = in_sizes[2];
  const int* srcp = ei;
  const int* dstp = ei + E;

  char* base = (char*)d_ws;
  size_t off = 0;
  auto alloc = [&](size_t bytes) -> void* {
    off = (off + 255) & ~(size_t)255;
    void* p = base + off;
    off += bytes;
    return p;
  };
  float* dinv     = (float*)alloc((size_t)n * sizeof(float));
  int*   cnt      = (int*)alloc((size_t)n * sizeof(int));
  int*   rowptr   = (int*)alloc((size_t)(n + 1) * sizeof(int));
  int*   fill     = (int*)alloc((size_t)n * sizeof(int));
  int*   partials = (int*)alloc(1024 * sizeof(int));
  int2*  colw     = (int2*)alloc((size_t)E * sizeof(int2));
  u16*   Wt1h     = (u16*)alloc((size_t)128 * 256 * sizeof(u16));
  u16*   Wt1l     = (u16*)alloc((size_t)128 * 256 * sizeof(u16));
  u16*   Wt2h     = (u16*)alloc((size_t)128 * 128 * sizeof(u16));
  u16*   Wt2l     = (u16*)alloc((size_t)128 * 128 * sizeof(u16));
  float* bufA     = (float*)alloc((size_t)n * COUT * sizeof(float));
  float* bufB     = (float*)alloc((size_t)n * COUT * sizeof(float));

  const int tb = 256;
  const int ntile = (n + 1023) / 1024;

  init_kernel<<<(n + tb - 1) / tb, tb, 0, stream>>>(dinv, cnt, n);
  edge_count_kernel<<<(E + tb - 1) / tb, tb, 0, stream>>>(dstp, ew, dinv, cnt, E);
  rsqrt_kernel<<<(n + tb - 1) / tb, tb, 0, stream>>>(dinv, n);
  scan1_kernel<<<ntile, 1024, 0, stream>>>(cnt, rowptr, partials, n);
  scan2_kernel<<<1, 1024, 0, stream>>>(partials, rowptr + n, ntile);
  scan3_kernel<<<(n + tb - 1) / tb, tb, 0, stream>>>(rowptr, fill, partials, n);
  scatter_kernel<<<(E + tb - 1) / tb, tb, 0, stream>>>(srcp, dstp, ew, dinv, fill, colw, E);

  prepw_kernel<<<(256 * COUT + 255) / 256, 256, 0, stream>>>(W1, Wt1h, Wt1l, 256);
  prepw_kernel<<<(128 * COUT + 255) / 256, 256, 0, stream>>>(W2, Wt2h, Wt2l, 128);

  const int gblk = (n + 63) / 64;
  // layer 1
  gemm_mfma_kernel<256><<<gblk, 256, 0, stream>>>(x, Wt1h, Wt1l, bufA, n);
  agg_kernel<<<(n + 3) / 4, 256, 0, stream>>>(bufA, dinv, rowptr, colw, b1, bufB, n);
  // layer 2
  gemm_mfma_kernel<128><<<gblk, 256, 0, stream>>>(bufB, Wt2h, Wt2l, bufA, n);
  agg_kernel<<<(n + 3) / 4, 256, 0, stream>>>(bufA, dinv, rowptr, colw, b2, out, n);
}

// Round 3
// 214.931 us; speedup vs baseline: 2.5278x; 1.3916x over previous
//
#include <hip/hip_runtime.h>

#define COUT 128  // both layers have 128 output channels

typedef unsigned short u16;
typedef unsigned int u32;
typedef unsigned long long u64;
typedef __attribute__((ext_vector_type(8))) short bf16x8;
typedef __attribute__((ext_vector_type(4))) float f32x4;

__device__ __forceinline__ u16 f2bf(float f) {
  u32 u = __builtin_bit_cast(u32, f);
  u += 0x7fffu + ((u >> 16) & 1u);  // round-to-nearest-even
  return (u16)(u >> 16);
}
__device__ __forceinline__ float bf2f(u16 h) {
  u32 u = ((u32)h) << 16;
  return __builtin_bit_cast(float, u);
}

// ---------------- graph preprocessing ----------------

__global__ void zero_kernel(u64* cnt64, int n) {
  int i = blockIdx.x * blockDim.x + threadIdx.x;
  if (i < n) cnt64[i] = 0ull;
}

// ONE u64 atomic per edge: high 24 bits = count (gives rank), low 40 bits = sum(ew) in 2^-24 fixed point.
__global__ void count_rank_kernel(const int* __restrict__ dst, const float* __restrict__ ew,
                                  u64* cnt64, u16* __restrict__ rank, int E) {
  int e = blockIdx.x * blockDim.x + threadIdx.x;
  if (e < E) {
    int d = dst[e];
    u64 add = (1ull << 40) | (u64)(u32)__float2uint_rn(ew[e] * 16777216.0f);
    u64 old = atomicAdd(&cnt64[d], add);
    rank[e] = (u16)(old >> 40);
  }
}

// scan pass 1: per-1024-tile exclusive scan of counts; also deg -> dinv (self-loop +1)
__global__ __launch_bounds__(1024) void scan1_kernel(const u64* __restrict__ cnt64,
                                                     int* __restrict__ exsc,
                                                     int* __restrict__ partials,
                                                     float* __restrict__ dinv, int n) {
  __shared__ int buf[1024];
  int tid = threadIdx.x;
  int i = blockIdx.x * 1024 + tid;
  int v = 0;
  if (i < n) {
    u64 c = cnt64[i];
    v = (int)(c >> 40);
    float deg = 1.0f + (float)(c & 0xFFFFFFFFFFull) * (1.0f / 16777216.0f);
    dinv[i] = rsqrtf(deg);
  }
  buf[tid] = v;
  __syncthreads();
  for (int off = 1; off < 1024; off <<= 1) {
    int t = (tid >= off) ? buf[tid - off] : 0;
    __syncthreads();
    buf[tid] += t;
    __syncthreads();
  }
  if (i < n) exsc[i] = buf[tid] - v;
  if (tid == 1023) partials[blockIdx.x] = buf[tid];
}

// scan pass 2: scan tile totals (nb <= 1024), write grand total to rowptr[n]
__global__ __launch_bounds__(1024) void scan2_kernel(int* partials, int* total_out, int nb) {
  __shared__ int buf[1024];
  int tid = threadIdx.x;
  int v = (tid < nb) ? partials[tid] : 0;
  buf[tid] = v;
  __syncthreads();
  for (int off = 1; off < 1024; off <<= 1) {
    int t = (tid >= off) ? buf[tid - off] : 0;
    __syncthreads();
    buf[tid] += t;
    __syncthreads();
  }
  if (tid < nb) partials[tid] = buf[tid] - v;
  if (tid == 1023) total_out[0] = buf[tid];
}

// scan pass 3: add tile offsets
__global__ void scan3_kernel(int* __restrict__ rowptr, const int* __restrict__ partials, int n) {
  int i = blockIdx.x * blockDim.x + threadIdx.x;
  if (i < n) rowptr[i] += partials[i >> 10];
}

// atomic-free scatter with normalization folded in
__global__ void scatter_kernel(const int* __restrict__ src, const int* __restrict__ dst,
                               const float* __restrict__ ew, const u16* __restrict__ rank,
                               const int* __restrict__ rowptr, const float* __restrict__ dinv,
                               int2* __restrict__ colw, int E) {
  int e = blockIdx.x * blockDim.x + threadIdx.x;
  if (e < E) {
    int s = src[e], d = dst[e];
    int pos = rowptr[d] + rank[e];
    int2 cw;
    cw.x = s;
    cw.y = __float_as_int(ew[e] * dinv[s] * dinv[d]);
    colw[pos] = cw;
  }
}

// ---------------- W prep: transpose + bf16 hi/lo split ----------------
__global__ void prepw_kernel(const float* __restrict__ W, u16* __restrict__ Wth,
                             u16* __restrict__ Wtl, int K) {
  int idx = blockIdx.x * 256 + threadIdx.x;
  if (idx >= K * COUT) return;
  int nn = idx / K, kk = idx - nn * K;
  float v = W[(size_t)kk * COUT + nn];
  u16 h = f2bf(v);
  Wth[idx] = h;
  Wtl[idx] = f2bf(v - bf2f(h));
}

// ---------------- MFMA GEMM: H[n][128](bf16) = A[n][CIN](fp32) @ W[CIN][128] ----------------
// bf16 hi/lo split (3 MFMA products). Tile BM=64,BN=128,BK=32; 4 waves 2x2.
// LDS 16B chunks XOR-swizzled -> ds_read_b128 fragment reads are 2-way (free).
template <int CIN>
__global__ __launch_bounds__(256) void gemm_mfma_kernel(const float* __restrict__ A,
                                                        const u16* __restrict__ Wth,
                                                        const u16* __restrict__ Wtl,
                                                        u16* __restrict__ H, int n) {
  __shared__ u16 Ah[64 * 32], Al[64 * 32], Bh[128 * 32], Bl[128 * 32];
  const int tid = threadIdx.x;
  const int row0 = blockIdx.x * 64;
  const int lane = tid & 63;
  const int w = tid >> 6;
  const int wr = w >> 1, wc = w & 1;
  const int r15 = lane & 15, q4 = lane >> 4;
  const int swz = q4 ^ ((r15 >> 1) & 3);

  f32x4 acc[2][4] = {};

  const int arow = tid >> 2, ac = tid & 3;
  const int sw_a = ac ^ ((arow >> 1) & 3);
  const bool arow_ok = (row0 + arow) < n;
  const float* aptr = A + (size_t)(row0 + arow) * CIN + ac * 8;

  for (int k0 = 0; k0 < CIN; k0 += 32) {
    if (k0) __syncthreads();
    float v[8];
    if (arow_ok) {
      float4 p0 = *(const float4*)(aptr + k0);
      float4 p1 = *(const float4*)(aptr + k0 + 4);
      v[0] = p0.x; v[1] = p0.y; v[2] = p0.z; v[3] = p0.w;
      v[4] = p1.x; v[5] = p1.y; v[6] = p1.z; v[7] = p1.w;
    } else {
#pragma unroll
      for (int j = 0; j < 8; ++j) v[j] = 0.f;
    }
    bf16x8 hv, lv;
#pragma unroll
    for (int j = 0; j < 8; ++j) {
      u16 h = f2bf(v[j]);
      hv[j] = (short)h;
      lv[j] = (short)f2bf(v[j] - bf2f(h));
    }
    *(bf16x8*)&Ah[arow * 32 + sw_a * 8] = hv;
    *(bf16x8*)&Al[arow * 32 + sw_a * 8] = lv;
#pragma unroll
    for (int rep = 0; rep < 2; ++rep) {
      int q = tid + rep * 256;
      int nrow = q >> 2, cd = q & 3;
      int dst = nrow * 32 + (cd ^ ((nrow >> 1) & 3)) * 8;
      *(bf16x8*)&Bh[dst] = *(const bf16x8*)(Wth + (size_t)nrow * CIN + k0 + cd * 8);
      *(bf16x8*)&Bl[dst] = *(const bf16x8*)(Wtl + (size_t)nrow * CIN + k0 + cd * 8);
    }
    __syncthreads();
    bf16x8 aH[2], aL[2], bH[4], bL[4];
#pragma unroll
    for (int mt = 0; mt < 2; ++mt) {
      int r = wr * 32 + mt * 16 + r15;
      int off = r * 32 + swz * 8;
      aH[mt] = *(bf16x8*)&Ah[off];
      aL[mt] = *(bf16x8*)&Al[off];
    }
#pragma unroll
    for (int nt = 0; nt < 4; ++nt) {
      int nn = wc * 64 + nt * 16 + r15;
      int off = nn * 32 + swz * 8;
      bH[nt] = *(bf16x8*)&Bh[off];
      bL[nt] = *(bf16x8*)&Bl[off];
    }
#pragma unroll
    for (int mt = 0; mt < 2; ++mt)
#pragma unroll
      for (int nt = 0; nt < 4; ++nt) {
        acc[mt][nt] = __builtin_amdgcn_mfma_f32_16x16x32_bf16(aH[mt], bH[nt], acc[mt][nt], 0, 0, 0);
        acc[mt][nt] = __builtin_amdgcn_mfma_f32_16x16x32_bf16(aH[mt], bL[nt], acc[mt][nt], 0, 0, 0);
        acc[mt][nt] = __builtin_amdgcn_mfma_f32_16x16x32_bf16(aL[mt], bH[nt], acc[mt][nt], 0, 0, 0);
      }
  }
  // epilogue: C/D layout col=lane&15, row=(lane>>4)*4+reg; store bf16
#pragma unroll
  for (int mt = 0; mt < 2; ++mt) {
    int rbase = row0 + wr * 32 + mt * 16 + q4 * 4;
#pragma unroll
    for (int nt = 0; nt < 4; ++nt) {
      int col = wc * 64 + nt * 16 + r15;
#pragma unroll
      for (int j = 0; j < 4; ++j) {
        int r = rbase + j;
        if (r < n) H[(size_t)r * COUT + col] = f2bf(acc[mt][nt][j]);
      }
    }
  }
}

// ---------------- aggregation: out = relu(b + dinv^2*h[i] + sum_e w*h[col]) ----------------
// 1 wave per node; h is bf16 [n][128]; lane holds channels {2*lane, 2*lane+1} via one u32 load.
__global__ __launch_bounds__(256) void agg_kernel(const u32* __restrict__ h,
                                                  const float* __restrict__ dinv,
                                                  const int* __restrict__ rowptr,
                                                  const int2* __restrict__ colw,
                                                  const float* __restrict__ bias,
                                                  float* __restrict__ out, int n) {
  int node = blockIdx.x * 4 + (threadIdx.x >> 6);
  if (node >= n) return;
  int lane = threadIdx.x & 63;
  float di = dinv[node];
  u32 hw = h[(size_t)node * 64 + lane];
  float ax = di * di * __builtin_bit_cast(float, hw << 16);
  float ay = di * di * __builtin_bit_cast(float, hw & 0xffff0000u);
  int e = rowptr[node], end = rowptr[node + 1];
  for (; e + 1 < end; e += 2) {
    int2 c0 = colw[e], c1 = colw[e + 1];
    u32 v0 = h[(size_t)c0.x * 64 + lane];
    u32 v1 = h[(size_t)c1.x * 64 + lane];
    float w0 = __int_as_float(c0.y), w1 = __int_as_float(c1.y);
    ax += w0 * __builtin_bit_cast(float, v0 << 16);
    ay += w0 * __builtin_bit_cast(float, v0 & 0xffff0000u);
    ax += w1 * __builtin_bit_cast(float, v1 << 16);
    ay += w1 * __builtin_bit_cast(float, v1 & 0xffff0000u);
  }
  if (e < end) {
    int2 c0 = colw[e];
    u32 v0 = h[(size_t)c0.x * 64 + lane];
    float w0 = __int_as_float(c0.y);
    ax += w0 * __builtin_bit_cast(float, v0 << 16);
    ay += w0 * __builtin_bit_cast(float, v0 & 0xffff0000u);
  }
  float2 bv = ((const float2*)bias)[lane];
  float2 o;
  o.x = fmaxf(ax + bv.x, 0.f);
  o.y = fmaxf(ay + bv.y, 0.f);
  ((float2*)(out + (size_t)node * COUT))[lane] = o;
}

// ---------------- launch ----------------

extern "C" void kernel_launch(void* const* d_in, const int* in_sizes, int n_in,
                              void* d_out, int out_size, void* d_ws, size_t ws_size,
                              hipStream_t stream) {
  const float* x  = (const float*)d_in[0];
  const int*   ei = (const int*)d_in[1];
  const float* ew = (const float*)d_in[2];
  const float* W1 = (const float*)d_in[3];
  const float* b1 = (const float*)d_in[4];
  const float* W2 = (const float*)d_in[5];
  const float* b2 = (const float*)d_in[6];
  float* out = (float*)d_out;

  const int cin = 256;
  const int n = in_sizes[0] / cin;
  const int E = in_sizes[2];
  const int* srcp = ei;
  const int* dstp = ei + E;

  char* base = (char*)d_ws;
  size_t off = 0;
  auto alloc = [&](size_t bytes) -> void* {
    off = (off + 255) & ~(size_t)255;
    void* p = base + off;
    off += bytes;
    return p;
  };
  u64*   cnt64    = (u64*)alloc((size_t)n * sizeof(u64));
  u16*   rank     = (u16*)alloc((size_t)E * sizeof(u16));
  int*   rowptr   = (int*)alloc((size_t)(n + 1) * sizeof(int));
  int*   partials = (int*)alloc(1024 * sizeof(int));
  float* dinv     = (float*)alloc((size_t)n * sizeof(float));
  int2*  colw     = (int2*)alloc((size_t)E * sizeof(int2));
  u16*   Wt1h     = (u16*)alloc((size_t)128 * 256 * sizeof(u16));
  u16*   Wt1l     = (u16*)alloc((size_t)128 * 256 * sizeof(u16));
  u16*   Wt2h     = (u16*)alloc((size_t)128 * 128 * sizeof(u16));
  u16*   Wt2l     = (u16*)alloc((size_t)128 * 128 * sizeof(u16));
  u16*   h16      = (u16*)alloc((size_t)n * COUT * sizeof(u16));   // bf16 h (both layers)
  float* o1       = (float*)alloc((size_t)n * COUT * sizeof(float));  // layer-1 output fp32

  const int tb = 256;
  const int ntile = (n + 1023) / 1024;

  zero_kernel<<<(n + tb - 1) / tb, tb, 0, stream>>>(cnt64, n);
  count_rank_kernel<<<(E + tb - 1) / tb, tb, 0, stream>>>(dstp, ew, cnt64, rank, E);
  scan1_kernel<<<ntile, 1024, 0, stream>>>(cnt64, rowptr, partials, dinv, n);
  scan2_kernel<<<1, 1024, 0, stream>>>(partials, rowptr + n, ntile);
  scan3_kernel<<<(n + tb - 1) / tb, tb, 0, stream>>>(rowptr, partials, n);
  scatter_kernel<<<(E + tb - 1) / tb, tb, 0, stream>>>(srcp, dstp, ew, rank, rowptr, dinv, colw, E);

  prepw_kernel<<<(256 * COUT + 255) / 256, 256, 0, stream>>>(W1, Wt1h, Wt1l, 256);
  prepw_kernel<<<(128 * COUT + 255) / 256, 256, 0, stream>>>(W2, Wt2h, Wt2l, 128);

  const int gblk = (n + 63) / 64;
  // layer 1
  gemm_mfma_kernel<256><<<gblk, 256, 0, stream>>>(x, Wt1h, Wt1l, h16, n);
  agg_kernel<<<(n + 3) / 4, 256, 0, stream>>>((const u32*)h16, dinv, rowptr, colw, b1, o1, n);
  // layer 2
  gemm_mfma_kernel<128><<<gblk, 256, 0, stream>>>(o1, Wt2h, Wt2l, h16, n);
  agg_kernel<<<(n + 3) / 4, 256, 0, stream>>>((const u32*)h16, dinv, rowptr, colw, b2, out, n);
}

// Round 4
// 179.865 us; speedup vs baseline: 3.0206x; 1.1950x over previous
//
#include <hip/hip_runtime.h>

#define COUT 128  // both layers have 128 output channels

typedef unsigned short u16;
typedef unsigned int u32;
typedef unsigned long long u64;
typedef __attribute__((ext_vector_type(8))) short bf16x8;
typedef __attribute__((ext_vector_type(4))) float f32x4;

__device__ __forceinline__ u16 f2bf(float f) {
  u32 u = __builtin_bit_cast(u32, f);
  u += 0x7fffu + ((u >> 16) & 1u);  // round-to-nearest-even
  return (u16)(u >> 16);
}
__device__ __forceinline__ float bf2f(u16 h) {
  u32 u = ((u32)h) << 16;
  return __builtin_bit_cast(float, u);
}

// ---------------- graph preprocessing ----------------

__global__ void zero_kernel(u64* cnt64, int n) {
  int i = blockIdx.x * blockDim.x + threadIdx.x;
  if (i < n) cnt64[i] = 0ull;
}

// ONE u64 atomic per edge: high 24 bits = count (gives rank), low 40 bits = sum(ew) in 2^-24 fixed point.
__global__ void count_rank_kernel(const int* __restrict__ dst, const float* __restrict__ ew,
                                  u64* cnt64, u16* __restrict__ rank, int E) {
  int e = blockIdx.x * blockDim.x + threadIdx.x;
  if (e < E) {
    int d = dst[e];
    u64 add = (1ull << 40) | (u64)(u32)__float2uint_rn(ew[e] * 16777216.0f);
    u64 old = atomicAdd(&cnt64[d], add);
    rank[e] = (u16)(old >> 40);
  }
}

// scan pass 1: per-1024-tile exclusive scan of counts; also deg -> dinv (self-loop +1)
__global__ __launch_bounds__(1024) void scan1_kernel(const u64* __restrict__ cnt64,
                                                     int* __restrict__ exsc,
                                                     int* __restrict__ partials,
                                                     float* __restrict__ dinv, int n) {
  __shared__ int buf[1024];
  int tid = threadIdx.x;
  int i = blockIdx.x * 1024 + tid;
  int v = 0;
  if (i < n) {
    u64 c = cnt64[i];
    v = (int)(c >> 40);
    float deg = 1.0f + (float)(c & 0xFFFFFFFFFFull) * (1.0f / 16777216.0f);
    dinv[i] = rsqrtf(deg);
  }
  buf[tid] = v;
  __syncthreads();
  for (int off = 1; off < 1024; off <<= 1) {
    int t = (tid >= off) ? buf[tid - off] : 0;
    __syncthreads();
    buf[tid] += t;
    __syncthreads();
  }
  if (i < n) exsc[i] = buf[tid] - v;
  if (tid == 1023) partials[blockIdx.x] = buf[tid];
}

// scan pass 2: scan tile totals (nb <= 1024), write grand total to rowptr[n]
__global__ __launch_bounds__(1024) void scan2_kernel(int* partials, int* total_out, int nb) {
  __shared__ int buf[1024];
  int tid = threadIdx.x;
  int v = (tid < nb) ? partials[tid] : 0;
  buf[tid] = v;
  __syncthreads();
  for (int off = 1; off < 1024; off <<= 1) {
    int t = (tid >= off) ? buf[tid - off] : 0;
    __syncthreads();
    buf[tid] += t;
    __syncthreads();
  }
  if (tid < nb) partials[tid] = buf[tid] - v;
  if (tid == 1023) total_out[0] = buf[tid];
}

// scan pass 3: add tile offsets
__global__ void scan3_kernel(int* __restrict__ rowptr, const int* __restrict__ partials, int n) {
  int i = blockIdx.x * blockDim.x + threadIdx.x;
  if (i < n) rowptr[i] += partials[i >> 10];
}

// atomic-free scatter with normalization folded in
__global__ void scatter_kernel(const int* __restrict__ src, const int* __restrict__ dst,
                               const float* __restrict__ ew, const u16* __restrict__ rank,
                               const int* __restrict__ rowptr, const float* __restrict__ dinv,
                               int2* __restrict__ colw, int E) {
  int e = blockIdx.x * blockDim.x + threadIdx.x;
  if (e < E) {
    int s = src[e], d = dst[e];
    int pos = rowptr[d] + rank[e];
    int2 cw;
    cw.x = s;
    cw.y = __float_as_int(ew[e] * dinv[s] * dinv[d]);
    colw[pos] = cw;
  }
}

// ---------------- W prep: transpose + bf16 hi/lo split ----------------
__global__ void prepw_kernel(const float* __restrict__ W, u16* __restrict__ Wth,
                             u16* __restrict__ Wtl, int K) {
  int idx = blockIdx.x * 256 + threadIdx.x;
  if (idx >= K * COUT) return;
  int nn = idx / K, kk = idx - nn * K;
  float v = W[(size_t)kk * COUT + nn];
  u16 h = f2bf(v);
  Wth[idx] = h;
  Wtl[idx] = f2bf(v - bf2f(h));
}

// ---------------- MFMA GEMM: H[n][128](bf16) = A[n][CIN] @ W[CIN][128] ----------------
// A fp32 (ABF16=false): bf16 hi/lo split, 3 MFMA products.
// A bf16 (ABF16=true): direct, 2 MFMA products (AhBh + AhBl).
// Tile BM=64,BN=128,BK=32; 4 waves 2x2. LDS 16B chunks XOR-swizzled (2-way = free).
template <int CIN, bool ABF16>
__global__ __launch_bounds__(256) void gemm_mfma_kernel(const void* __restrict__ Av,
                                                        const u16* __restrict__ Wth,
                                                        const u16* __restrict__ Wtl,
                                                        u16* __restrict__ H, int n) {
  __shared__ u16 Ah[64 * 32];
  __shared__ u16 Al[ABF16 ? 16 : 64 * 32];
  __shared__ u16 Bh[128 * 32], Bl[128 * 32];
  const int tid = threadIdx.x;
  const int row0 = blockIdx.x * 64;
  const int lane = tid & 63;
  const int w = tid >> 6;
  const int wr = w >> 1, wc = w & 1;
  const int r15 = lane & 15, q4 = lane >> 4;
  const int swz = q4 ^ ((r15 >> 1) & 3);

  f32x4 acc[2][4] = {};

  const int arow = tid >> 2, ac = tid & 3;
  const int sw_a = ac ^ ((arow >> 1) & 3);
  const bool arow_ok = (row0 + arow) < n;

  for (int k0 = 0; k0 < CIN; k0 += 32) {
    if (k0) __syncthreads();
    if constexpr (ABF16) {
      const u16* A = (const u16*)Av;
      bf16x8 hv = {};
      if (arow_ok) hv = *(const bf16x8*)(A + (size_t)(row0 + arow) * CIN + k0 + ac * 8);
      *(bf16x8*)&Ah[arow * 32 + sw_a * 8] = hv;
    } else {
      const float* A = (const float*)Av;
      float v[8];
      if (arow_ok) {
        const float* aptr = A + (size_t)(row0 + arow) * CIN + k0 + ac * 8;
        float4 p0 = *(const float4*)aptr;
        float4 p1 = *(const float4*)(aptr + 4);
        v[0] = p0.x; v[1] = p0.y; v[2] = p0.z; v[3] = p0.w;
        v[4] = p1.x; v[5] = p1.y; v[6] = p1.z; v[7] = p1.w;
      } else {
#pragma unroll
        for (int j = 0; j < 8; ++j) v[j] = 0.f;
      }
      bf16x8 hv, lv;
#pragma unroll
      for (int j = 0; j < 8; ++j) {
        u16 h = f2bf(v[j]);
        hv[j] = (short)h;
        lv[j] = (short)f2bf(v[j] - bf2f(h));
      }
      *(bf16x8*)&Ah[arow * 32 + sw_a * 8] = hv;
      *(bf16x8*)&Al[arow * 32 + sw_a * 8] = lv;
    }
#pragma unroll
    for (int rep = 0; rep < 2; ++rep) {
      int q = tid + rep * 256;
      int nrow = q >> 2, cd = q & 3;
      int dst = nrow * 32 + (cd ^ ((nrow >> 1) & 3)) * 8;
      *(bf16x8*)&Bh[dst] = *(const bf16x8*)(Wth + (size_t)nrow * CIN + k0 + cd * 8);
      *(bf16x8*)&Bl[dst] = *(const bf16x8*)(Wtl + (size_t)nrow * CIN + k0 + cd * 8);
    }
    __syncthreads();
    bf16x8 aH[2], aL[2], bH[4], bL[4];
#pragma unroll
    for (int mt = 0; mt < 2; ++mt) {
      int r = wr * 32 + mt * 16 + r15;
      int off = r * 32 + swz * 8;
      aH[mt] = *(bf16x8*)&Ah[off];
      if constexpr (!ABF16) aL[mt] = *(bf16x8*)&Al[off];
    }
#pragma unroll
    for (int nt = 0; nt < 4; ++nt) {
      int nn = wc * 64 + nt * 16 + r15;
      int off = nn * 32 + swz * 8;
      bH[nt] = *(bf16x8*)&Bh[off];
      bL[nt] = *(bf16x8*)&Bl[off];
    }
#pragma unroll
    for (int mt = 0; mt < 2; ++mt)
#pragma unroll
      for (int nt = 0; nt < 4; ++nt) {
        acc[mt][nt] = __builtin_amdgcn_mfma_f32_16x16x32_bf16(aH[mt], bH[nt], acc[mt][nt], 0, 0, 0);
        acc[mt][nt] = __builtin_amdgcn_mfma_f32_16x16x32_bf16(aH[mt], bL[nt], acc[mt][nt], 0, 0, 0);
        if constexpr (!ABF16)
          acc[mt][nt] = __builtin_amdgcn_mfma_f32_16x16x32_bf16(aL[mt], bH[nt], acc[mt][nt], 0, 0, 0);
      }
  }
  // epilogue: C/D layout col=lane&15, row=(lane>>4)*4+reg; store bf16
#pragma unroll
  for (int mt = 0; mt < 2; ++mt) {
    int rbase = row0 + wr * 32 + mt * 16 + q4 * 4;
#pragma unroll
    for (int nt = 0; nt < 4; ++nt) {
      int col = wc * 64 + nt * 16 + r15;
#pragma unroll
      for (int j = 0; j < 4; ++j) {
        int r = rbase + j;
        if (r < n) H[(size_t)r * COUT + col] = f2bf(acc[mt][nt][j]);
      }
    }
  }
}

// ---------------- aggregation: out = relu(b + dinv^2*h[i] + sum_e w*h[col]) ----------------
// 1 wave per node; 4 groups of 16 lanes; each group loads a full 256B bf16 row
// (16B/lane) for one edge -> 8 edges in flight per iteration (unroll 2).
// Cross-group butterfly reduce at the end.
__device__ __forceinline__ void acc8(const uint4& hv, float w, float* acc) {
  u32 a0 = hv.x, a1 = hv.y, a2 = hv.z, a3 = hv.w;
  acc[0] += w * __builtin_bit_cast(float, a0 << 16);
  acc[1] += w * __builtin_bit_cast(float, a0 & 0xffff0000u);
  acc[2] += w * __builtin_bit_cast(float, a1 << 16);
  acc[3] += w * __builtin_bit_cast(float, a1 & 0xffff0000u);
  acc[4] += w * __builtin_bit_cast(float, a2 << 16);
  acc[5] += w * __builtin_bit_cast(float, a2 & 0xffff0000u);
  acc[6] += w * __builtin_bit_cast(float, a3 << 16);
  acc[7] += w * __builtin_bit_cast(float, a3 & 0xffff0000u);
}

template <bool BF16_OUT>
__global__ __launch_bounds__(256) void agg_kernel(const uint4* __restrict__ h,  // bf16 rows, 16 uint4/row
                                                  const float* __restrict__ dinv,
                                                  const int* __restrict__ rowptr,
                                                  const int2* __restrict__ colw,
                                                  const float* __restrict__ bias,
                                                  void* __restrict__ outp, int n) {
  int node = blockIdx.x * 4 + (threadIdx.x >> 6);
  if (node >= n) return;
  int lane = threadIdx.x & 63;
  int g = lane >> 4, sub = lane & 15;
  float di = dinv[node];
  float acc[8] = {};
  // self-loop: all lanes load own row; only group 0 weights it
  uint4 own = h[(size_t)node * 16 + sub];
  acc8(own, (g == 0) ? di * di : 0.f, acc);
  int beg = rowptr[node], end = rowptr[node + 1];
  for (int base = beg; base < end; base += 8) {
    int e0 = base + g, e1 = base + 4 + g;
    int2 c0 = (e0 < end) ? colw[e0] : make_int2(node, 0);
    int2 c1 = (e1 < end) ? colw[e1] : make_int2(node, 0);
    uint4 v0 = h[(size_t)c0.x * 16 + sub];
    uint4 v1 = h[(size_t)c1.x * 16 + sub];
    acc8(v0, __int_as_float(c0.y), acc);
    acc8(v1, __int_as_float(c1.y), acc);
  }
  // butterfly: sum the 4 groups (xor 16, 32)
#pragma unroll
  for (int j = 0; j < 8; ++j) {
    acc[j] += __shfl_xor(acc[j], 16);
    acc[j] += __shfl_xor(acc[j], 32);
  }
  // lane writes channels c0 = sub*8 + g*2, c0+1
  int c0 = sub * 8 + g * 2;
  float2 bv = *(const float2*)(bias + c0);
  float r0 = fmaxf(acc[g * 2] + bv.x, 0.f);
  float r1 = fmaxf(acc[g * 2 + 1] + bv.y, 0.f);
  if constexpr (BF16_OUT) {
    ((u32*)outp)[(size_t)node * 64 + (c0 >> 1)] = (u32)f2bf(r0) | ((u32)f2bf(r1) << 16);
  } else {
    *(float2*)((float*)outp + (size_t)node * COUT + c0) = make_float2(r0, r1);
  }
}

// ---------------- launch ----------------

extern "C" void kernel_launch(void* const* d_in, const int* in_sizes, int n_in,
                              void* d_out, int out_size, void* d_ws, size_t ws_size,
                              hipStream_t stream) {
  const float* x  = (const float*)d_in[0];
  const int*   ei = (const int*)d_in[1];
  const float* ew = (const float*)d_in[2];
  const float* W1 = (const float*)d_in[3];
  const float* b1 = (const float*)d_in[4];
  const float* W2 = (const float*)d_in[5];
  const float* b2 = (const float*)d_in[6];
  float* out = (float*)d_out;

  const int cin = 256;
  const int n = in_sizes[0] / cin;
  const int E = in_sizes[2];
  const int* srcp = ei;
  const int* dstp = ei + E;

  char* base = (char*)d_ws;
  size_t off = 0;
  auto alloc = [&](size_t bytes) -> void* {
    off = (off + 255) & ~(size_t)255;
    void* p = base + off;
    off += bytes;
    return p;
  };
  u64*   cnt64    = (u64*)alloc((size_t)n * sizeof(u64));
  u16*   rank     = (u16*)alloc((size_t)E * sizeof(u16));
  int*   rowptr   = (int*)alloc((size_t)(n + 1) * sizeof(int));
  int*   partials = (int*)alloc(1024 * sizeof(int));
  float* dinv     = (float*)alloc((size_t)n * sizeof(float));
  int2*  colw     = (int2*)alloc((size_t)E * sizeof(int2));
  u16*   Wt1h     = (u16*)alloc((size_t)128 * 256 * sizeof(u16));
  u16*   Wt1l     = (u16*)alloc((size_t)128 * 256 * sizeof(u16));
  u16*   Wt2h     = (u16*)alloc((size_t)128 * 128 * sizeof(u16));
  u16*   Wt2l     = (u16*)alloc((size_t)128 * 128 * sizeof(u16));
  u16*   h16      = (u16*)alloc((size_t)n * COUT * sizeof(u16));  // gemm output (both layers)
  u16*   o1b      = (u16*)alloc((size_t)n * COUT * sizeof(u16));  // layer-1 activations (bf16)

  const int tb = 256;
  const int ntile = (n + 1023) / 1024;

  zero_kernel<<<(n + tb - 1) / tb, tb, 0, stream>>>(cnt64, n);
  count_rank_kernel<<<(E + tb - 1) / tb, tb, 0, stream>>>(dstp, ew, cnt64, rank, E);
  scan1_kernel<<<ntile, 1024, 0, stream>>>(cnt64, rowptr, partials, dinv, n);
  scan2_kernel<<<1, 1024, 0, stream>>>(partials, rowptr + n, ntile);
  scan3_kernel<<<(n + tb - 1) / tb, tb, 0, stream>>>(rowptr, partials, n);
  scatter_kernel<<<(E + tb - 1) / tb, tb, 0, stream>>>(srcp, dstp, ew, rank, rowptr, dinv, colw, E);

  prepw_kernel<<<(256 * COUT + 255) / 256, 256, 0, stream>>>(W1, Wt1h, Wt1l, 256);
  prepw_kernel<<<(128 * COUT + 255) / 256, 256, 0, stream>>>(W2, Wt2h, Wt2l, 128);

  const int gblk = (n + 63) / 64;
  const int ablk = (n + 3) / 4;
  // layer 1
  gemm_mfma_kernel<256, false><<<gblk, 256, 0, stream>>>(x, Wt1h, Wt1l, h16, n);
  agg_kernel<true><<<ablk, 256, 0, stream>>>((const uint4*)h16, dinv, rowptr, colw, b1, o1b, n);
  // layer 2
  gemm_mfma_kernel<128, true><<<gblk, 256, 0, stream>>>(o1b, Wt2h, Wt2l, h16, n);
  agg_kernel<false><<<ablk, 256, 0, stream>>>((const uint4*)h16, dinv, rowptr, colw, b2, out, n);
}

// Round 5
// 172.730 us; speedup vs baseline: 3.1454x; 1.0413x over previous
//
#include <hip/hip_runtime.h>

#define COUT 128  // both layers have 128 output channels

typedef unsigned short u16;
typedef unsigned int u32;
typedef unsigned long long u64;
typedef __attribute__((ext_vector_type(8))) short bf16x8;
typedef __attribute__((ext_vector_type(4))) float f32x4;

__device__ __forceinline__ u16 f2bf(float f) {
  u32 u = __builtin_bit_cast(u32, f);
  u += 0x7fffu + ((u >> 16) & 1u);  // round-to-nearest-even
  return (u16)(u >> 16);
}
__device__ __forceinline__ float bf2f(u16 h) {
  u32 u = ((u32)h) << 16;
  return __builtin_bit_cast(float, u);
}

// ---------------- fused setup: zero padded counters + prep W1 + prep W2 ----------------
// cnt64 is padded: counter i lives at cnt64[i*8] (one per 64B line) to kill
// atomic line-contention serialization.
__global__ void init_kernel(u64* __restrict__ cnt64, int n8,
                            const float* __restrict__ W1, u16* __restrict__ Wt1h, u16* __restrict__ Wt1l,
                            const float* __restrict__ W2, u16* __restrict__ Wt2h, u16* __restrict__ Wt2l,
                            int zb, int w1b) {
  int b = blockIdx.x;
  if (b < zb) {
    int i = b * 256 + threadIdx.x;
    if (i < n8) cnt64[i] = 0ull;
  } else if (b < zb + w1b) {
    int idx = (b - zb) * 256 + threadIdx.x;  // W1: K=256
    int nn = idx >> 8, kk = idx & 255;
    float v = W1[(size_t)kk * COUT + nn];
    u16 h = f2bf(v);
    Wt1h[idx] = h;
    Wt1l[idx] = f2bf(v - bf2f(h));
  } else {
    int idx = (b - zb - w1b) * 256 + threadIdx.x;  // W2: K=128
    int nn = idx >> 7, kk = idx & 127;
    float v = W2[(size_t)kk * COUT + nn];
    u16 h = f2bf(v);
    Wt2h[idx] = h;
    Wt2l[idx] = f2bf(v - bf2f(h));
  }
}

// ONE u64 atomic per edge into a line-padded counter:
// high 24 bits = count (gives rank), low 40 bits = sum(ew) in 2^-24 fixed point.
__global__ void count_rank_kernel(const int* __restrict__ dst, const float* __restrict__ ew,
                                  u64* cnt64, u16* __restrict__ rank, int E) {
  int e = blockIdx.x * blockDim.x + threadIdx.x;
  if (e < E) {
    int d = dst[e];
    u64 add = (1ull << 40) | (u64)(u32)__float2uint_rn(ew[e] * 16777216.0f);
    u64 old = atomicAdd(&cnt64[(size_t)d * 8], add);
    rank[e] = (u16)(old >> 40);
  }
}

// scan pass 1: per-1024-tile exclusive scan of counts; also deg -> dinv (self-loop +1)
__global__ __launch_bounds__(1024) void scan1_kernel(const u64* __restrict__ cnt64,
                                                     int* __restrict__ exsc,
                                                     int* __restrict__ partials,
                                                     float* __restrict__ dinv, int n) {
  __shared__ int buf[1024];
  int tid = threadIdx.x;
  int i = blockIdx.x * 1024 + tid;
  int v = 0;
  if (i < n) {
    u64 c = cnt64[(size_t)i * 8];
    v = (int)(c >> 40);
    float deg = 1.0f + (float)(c & 0xFFFFFFFFFFull) * (1.0f / 16777216.0f);
    dinv[i] = rsqrtf(deg);
  }
  buf[tid] = v;
  __syncthreads();
  for (int off = 1; off < 1024; off <<= 1) {
    int t = (tid >= off) ? buf[tid - off] : 0;
    __syncthreads();
    buf[tid] += t;
    __syncthreads();
  }
  if (i < n) exsc[i] = buf[tid] - v;
  if (tid == 1023) partials[blockIdx.x] = buf[tid];
}

// scan pass 2: scan tile totals (nb <= 1024), write grand total to rowptr[n]
__global__ __launch_bounds__(1024) void scan2_kernel(int* partials, int* total_out, int nb) {
  __shared__ int buf[1024];
  int tid = threadIdx.x;
  int v = (tid < nb) ? partials[tid] : 0;
  buf[tid] = v;
  __syncthreads();
  for (int off = 1; off < 1024; off <<= 1) {
    int t = (tid >= off) ? buf[tid - off] : 0;
    __syncthreads();
    buf[tid] += t;
    __syncthreads();
  }
  if (tid < nb) partials[tid] = buf[tid] - v;
  if (tid == 1023) total_out[0] = buf[tid];
}

// scan pass 3: add tile offsets
__global__ void scan3_kernel(int* __restrict__ rowptr, const int* __restrict__ partials, int n) {
  int i = blockIdx.x * blockDim.x + threadIdx.x;
  if (i < n) rowptr[i] += partials[i >> 10];
}

// atomic-free scatter with normalization folded in
__global__ void scatter_kernel(const int* __restrict__ src, const int* __restrict__ dst,
                               const float* __restrict__ ew, const u16* __restrict__ rank,
                               const int* __restrict__ rowptr, const float* __restrict__ dinv,
                               int2* __restrict__ colw, int E) {
  int e = blockIdx.x * blockDim.x + threadIdx.x;
  if (e < E) {
    int s = src[e], d = dst[e];
    int pos = rowptr[d] + rank[e];
    int2 cw;
    cw.x = s;
    cw.y = __float_as_int(ew[e] * dinv[s] * dinv[d]);
    colw[pos] = cw;
  }
}

// ---------------- MFMA GEMM: H[n][128](bf16) = A[n][CIN] @ W[CIN][128] ----------------
// A fp32 (ABF16=false): bf16 hi/lo split, 3 MFMA products.
// A bf16 (ABF16=true): direct, 2 MFMA products (AhBh + AhBl).
// Tile BM=64,BN=128,BK=32; 4 waves 2x2. LDS 16B chunks XOR-swizzled (2-way = free).
template <int CIN, bool ABF16>
__global__ __launch_bounds__(256) void gemm_mfma_kernel(const void* __restrict__ Av,
                                                        const u16* __restrict__ Wth,
                                                        const u16* __restrict__ Wtl,
                                                        u16* __restrict__ H, int n) {
  __shared__ u16 Ah[64 * 32];
  __shared__ u16 Al[ABF16 ? 16 : 64 * 32];
  __shared__ u16 Bh[128 * 32], Bl[128 * 32];
  const int tid = threadIdx.x;
  const int row0 = blockIdx.x * 64;
  const int lane = tid & 63;
  const int w = tid >> 6;
  const int wr = w >> 1, wc = w & 1;
  const int r15 = lane & 15, q4 = lane >> 4;
  const int swz = q4 ^ ((r15 >> 1) & 3);

  f32x4 acc[2][4] = {};

  const int arow = tid >> 2, ac = tid & 3;
  const int sw_a = ac ^ ((arow >> 1) & 3);
  const bool arow_ok = (row0 + arow) < n;

  for (int k0 = 0; k0 < CIN; k0 += 32) {
    if (k0) __syncthreads();
    if constexpr (ABF16) {
      const u16* A = (const u16*)Av;
      bf16x8 hv = {};
      if (arow_ok) hv = *(const bf16x8*)(A + (size_t)(row0 + arow) * CIN + k0 + ac * 8);
      *(bf16x8*)&Ah[arow * 32 + sw_a * 8] = hv;
    } else {
      const float* A = (const float*)Av;
      float v[8];
      if (arow_ok) {
        const float* aptr = A + (size_t)(row0 + arow) * CIN + k0 + ac * 8;
        float4 p0 = *(const float4*)aptr;
        float4 p1 = *(const float4*)(aptr + 4);
        v[0] = p0.x; v[1] = p0.y; v[2] = p0.z; v[3] = p0.w;
        v[4] = p1.x; v[5] = p1.y; v[6] = p1.z; v[7] = p1.w;
      } else {
#pragma unroll
        for (int j = 0; j < 8; ++j) v[j] = 0.f;
      }
      bf16x8 hv, lv;
#pragma unroll
      for (int j = 0; j < 8; ++j) {
        u16 h = f2bf(v[j]);
        hv[j] = (short)h;
        lv[j] = (short)f2bf(v[j] - bf2f(h));
      }
      *(bf16x8*)&Ah[arow * 32 + sw_a * 8] = hv;
      *(bf16x8*)&Al[arow * 32 + sw_a * 8] = lv;
    }
#pragma unroll
    for (int rep = 0; rep < 2; ++rep) {
      int q = tid + rep * 256;
      int nrow = q >> 2, cd = q & 3;
      int dst = nrow * 32 + (cd ^ ((nrow >> 1) & 3)) * 8;
      *(bf16x8*)&Bh[dst] = *(const bf16x8*)(Wth + (size_t)nrow * CIN + k0 + cd * 8);
      *(bf16x8*)&Bl[dst] = *(const bf16x8*)(Wtl + (size_t)nrow * CIN + k0 + cd * 8);
    }
    __syncthreads();
    bf16x8 aH[2], aL[2], bH[4], bL[4];
#pragma unroll
    for (int mt = 0; mt < 2; ++mt) {
      int r = wr * 32 + mt * 16 + r15;
      int off = r * 32 + swz * 8;
      aH[mt] = *(bf16x8*)&Ah[off];
      if constexpr (!ABF16) aL[mt] = *(bf16x8*)&Al[off];
    }
#pragma unroll
    for (int nt = 0; nt < 4; ++nt) {
      int nn = wc * 64 + nt * 16 + r15;
      int off = nn * 32 + swz * 8;
      bH[nt] = *(bf16x8*)&Bh[off];
      bL[nt] = *(bf16x8*)&Bl[off];
    }
#pragma unroll
    for (int mt = 0; mt < 2; ++mt)
#pragma unroll
      for (int nt = 0; nt < 4; ++nt) {
        acc[mt][nt] = __builtin_amdgcn_mfma_f32_16x16x32_bf16(aH[mt], bH[nt], acc[mt][nt], 0, 0, 0);
        acc[mt][nt] = __builtin_amdgcn_mfma_f32_16x16x32_bf16(aH[mt], bL[nt], acc[mt][nt], 0, 0, 0);
        if constexpr (!ABF16)
          acc[mt][nt] = __builtin_amdgcn_mfma_f32_16x16x32_bf16(aL[mt], bH[nt], acc[mt][nt], 0, 0, 0);
      }
  }
  // epilogue: C/D layout col=lane&15, row=(lane>>4)*4+reg; store bf16
#pragma unroll
  for (int mt = 0; mt < 2; ++mt) {
    int rbase = row0 + wr * 32 + mt * 16 + q4 * 4;
#pragma unroll
    for (int nt = 0; nt < 4; ++nt) {
      int col = wc * 64 + nt * 16 + r15;
#pragma unroll
      for (int j = 0; j < 4; ++j) {
        int r = rbase + j;
        if (r < n) H[(size_t)r * COUT + col] = f2bf(acc[mt][nt][j]);
      }
    }
  }
}

// ---------------- aggregation: out = relu(b + dinv^2*h[i] + sum_e w*h[col]) ----------------
// 1 wave per node; 4 groups of 16 lanes; each group loads a full 256B bf16 row
// (16B/lane) per edge; unroll 4 -> 16 edge rows in flight per iteration.
// Tail dummies load the node's own row (L1-hot) with weight 0.
__device__ __forceinline__ void acc8(const uint4& hv, float w, float* acc) {
  u32 a0 = hv.x, a1 = hv.y, a2 = hv.z, a3 = hv.w;
  acc[0] += w * __builtin_bit_cast(float, a0 << 16);
  acc[1] += w * __builtin_bit_cast(float, a0 & 0xffff0000u);
  acc[2] += w * __builtin_bit_cast(float, a1 << 16);
  acc[3] += w * __builtin_bit_cast(float, a1 & 0xffff0000u);
  acc[4] += w * __builtin_bit_cast(float, a2 << 16);
  acc[5] += w * __builtin_bit_cast(float, a2 & 0xffff0000u);
  acc[6] += w * __builtin_bit_cast(float, a3 << 16);
  acc[7] += w * __builtin_bit_cast(float, a3 & 0xffff0000u);
}

template <bool BF16_OUT>
__global__ __launch_bounds__(256) void agg_kernel(const uint4* __restrict__ h,  // bf16 rows, 16 uint4/row
                                                  const float* __restrict__ dinv,
                                                  const int* __restrict__ rowptr,
                                                  const int2* __restrict__ colw,
                                                  const float* __restrict__ bias,
                                                  void* __restrict__ outp, int n) {
  int node = blockIdx.x * 4 + (threadIdx.x >> 6);
  if (node >= n) return;
  int lane = threadIdx.x & 63;
  int g = lane >> 4, sub = lane & 15;
  float di = dinv[node];
  float acc[8] = {};
  // self-loop: all lanes load own row; only group 0 weights it
  uint4 own = h[(size_t)node * 16 + sub];
  acc8(own, (g == 0) ? di * di : 0.f, acc);
  int beg = rowptr[node], end = rowptr[node + 1];
  for (int base = beg; base < end; base += 16) {
    int2 c0, c1, c2, c3;
    int e0 = base + g, e1 = base + 4 + g, e2 = base + 8 + g, e3 = base + 12 + g;
    c0 = (e0 < end) ? colw[e0] : make_int2(node, 0);
    c1 = (e1 < end) ? colw[e1] : make_int2(node, 0);
    c2 = (e2 < end) ? colw[e2] : make_int2(node, 0);
    c3 = (e3 < end) ? colw[e3] : make_int2(node, 0);
    uint4 v0 = h[(size_t)c0.x * 16 + sub];
    uint4 v1 = h[(size_t)c1.x * 16 + sub];
    uint4 v2 = h[(size_t)c2.x * 16 + sub];
    uint4 v3 = h[(size_t)c3.x * 16 + sub];
    acc8(v0, __int_as_float(c0.y), acc);
    acc8(v1, __int_as_float(c1.y), acc);
    acc8(v2, __int_as_float(c2.y), acc);
    acc8(v3, __int_as_float(c3.y), acc);
  }
  // butterfly: sum the 4 groups (xor 16, 32)
#pragma unroll
  for (int j = 0; j < 8; ++j) {
    acc[j] += __shfl_xor(acc[j], 16);
    acc[j] += __shfl_xor(acc[j], 32);
  }
  // lane writes channels c0 = sub*8 + g*2, c0+1
  int c0 = sub * 8 + g * 2;
  float2 bv = *(const float2*)(bias + c0);
  float r0 = fmaxf(acc[g * 2] + bv.x, 0.f);
  float r1 = fmaxf(acc[g * 2 + 1] + bv.y, 0.f);
  if constexpr (BF16_OUT) {
    ((u32*)outp)[(size_t)node * 64 + (c0 >> 1)] = (u32)f2bf(r0) | ((u32)f2bf(r1) << 16);
  } else {
    *(float2*)((float*)outp + (size_t)node * COUT + c0) = make_float2(r0, r1);
  }
}

// ---------------- launch ----------------

extern "C" void kernel_launch(void* const* d_in, const int* in_sizes, int n_in,
                              void* d_out, int out_size, void* d_ws, size_t ws_size,
                              hipStream_t stream) {
  const float* x  = (const float*)d_in[0];
  const int*   ei = (const int*)d_in[1];
  const float* ew = (const float*)d_in[2];
  const float* W1 = (const float*)d_in[3];
  const float* b1 = (const float*)d_in[4];
  const float* W2 = (const float*)d_in[5];
  const float* b2 = (const float*)d_in[6];
  float* out = (float*)d_out;

  const int cin = 256;
  const int n = in_sizes[0] / cin;
  const int E = in_sizes[2];
  const int* srcp = ei;
  const int* dstp = ei + E;

  char* base = (char*)d_ws;
  size_t off = 0;
  auto alloc = [&](size_t bytes) -> void* {
    off = (off + 255) & ~(size_t)255;
    void* p = base + off;
    off += bytes;
    return p;
  };
  u64*   cnt64    = (u64*)alloc((size_t)n * 8 * sizeof(u64));  // line-padded: counter i at [i*8]
  u16*   rank     = (u16*)alloc((size_t)E * sizeof(u16));
  int*   rowptr   = (int*)alloc((size_t)(n + 1) * sizeof(int));
  int*   partials = (int*)alloc(1024 * sizeof(int));
  float* dinv     = (float*)alloc((size_t)n * sizeof(float));
  int2*  colw     = (int2*)alloc((size_t)E * sizeof(int2));
  u16*   Wt1h     = (u16*)alloc((size_t)128 * 256 * sizeof(u16));
  u16*   Wt1l     = (u16*)alloc((size_t)128 * 256 * sizeof(u16));
  u16*   Wt2h     = (u16*)alloc((size_t)128 * 128 * sizeof(u16));
  u16*   Wt2l     = (u16*)alloc((size_t)128 * 128 * sizeof(u16));
  u16*   h16      = (u16*)alloc((size_t)n * COUT * sizeof(u16));  // gemm output (both layers)
  u16*   o1b      = (u16*)alloc((size_t)n * COUT * sizeof(u16));  // layer-1 activations (bf16)

  const int tb = 256;
  const int ntile = (n + 1023) / 1024;
  const int n8 = n * 8;
  const int zb = (n8 + 255) / 256;
  const int w1b = 256 * COUT / 256;  // 128 blocks
  const int w2b = 128 * COUT / 256;  // 64 blocks

  init_kernel<<<zb + w1b + w2b, tb, 0, stream>>>(cnt64, n8, W1, Wt1h, Wt1l, W2, Wt2h, Wt2l, zb, w1b);
  count_rank_kernel<<<(E + tb - 1) / tb, tb, 0, stream>>>(dstp, ew, cnt64, rank, E);
  scan1_kernel<<<ntile, 1024, 0, stream>>>(cnt64, rowptr, partials, dinv, n);
  scan2_kernel<<<1, 1024, 0, stream>>>(partials, rowptr + n, ntile);
  scan3_kernel<<<(n + tb - 1) / tb, tb, 0, stream>>>(rowptr, partials, n);
  scatter_kernel<<<(E + tb - 1) / tb, tb, 0, stream>>>(srcp, dstp, ew, rank, rowptr, dinv, colw, E);

  const int gblk = (n + 63) / 64;
  const int ablk = (n + 3) / 4;
  // layer 1
  gemm_mfma_kernel<256, false><<<gblk, 256, 0, stream>>>(x, Wt1h, Wt1l, h16, n);
  agg_kernel<true><<<ablk, 256, 0, stream>>>((const uint4*)h16, dinv, rowptr, colw, b1, o1b, n);
  // layer 2
  gemm_mfma_kernel<128, true><<<gblk, 256, 0, stream>>>(o1b, Wt2h, Wt2l, h16, n);
  agg_kernel<false><<<ablk, 256, 0, stream>>>((const uint4*)h16, dinv, rowptr, colw, b2, out, n);
}